// Round 1
// baseline (956.297 us; speedup 1.0000x reference)
//
#include <hip/hip_runtime.h>
#include <math.h>

#define HH 16
#define SS 2048
#define DD 64
#define GG 8
#define QB 32
#define KB 32
#define QE 37      // QB + 5 (conv query halo: -2..+3)
#define KE 42      // KB + 10 (conv key halo: -5..+5)
#define DP 68      // padded row stride (floats) for Q/K/V tiles: 16B-aligned, bank shift 4
#define SPITCH 43  // masked-score tile pitch
#define PPITCH 33  // P tile pitch
#define NT 64      // S / QB

#define FMA4(A, s, B)                 \
    do {                              \
        (A).x = fmaf((s), (B).x, (A).x); \
        (A).y = fmaf((s), (B).y, (A).y); \
        (A).z = fmaf((s), (B).z, (A).z); \
        (A).w = fmaf((s), (B).w, (A).w); \
    } while (0)

#define SCALE4(A, s)                  \
    do {                              \
        (A).x *= (s); (A).y *= (s);   \
        (A).z *= (s); (A).w *= (s);   \
    } while (0)

__global__ __launch_bounds__(256, 2)
void mta_fused(const float* __restrict__ Q, const float* __restrict__ K,
               const float* __restrict__ V, const float* __restrict__ CW,
               const float* __restrict__ CB, const float* __restrict__ MIX,
               const float* __restrict__ GAM, const float* __restrict__ BET,
               float* __restrict__ OUT)
{
    __shared__ __align__(16) float sQ[2 * QE * DP];   // 20128 B
    __shared__ __align__(16) float sKV[2 * KE * DP];  // 22848 B (K ext, then V reuses rows 0..31)
    __shared__ float sS[2 * QE * SPITCH];             // 12728 B masked scores (extended)
    __shared__ float sP[2 * QB * PPITCH];             // 8448 B exp(scores)
    __shared__ float sResc[2][QB];
    __shared__ float sL[2][QB];
    __shared__ float sW[2][66];
    __shared__ float sB[2];

    const int tid = threadIdx.x;
    const int g = blockIdx.x & 7;                  // group
    const int tile = (NT - 1) - (blockIdx.x >> 3); // heavy tiles dispatched first
    const int q0 = tile * QB;

    // conv weights + bias for this group's two heads
    for (int idx = tid; idx < 132; idx += 256) {
        int h = idx / 66, w = idx - h * 66;
        sW[h][w] = CW[(2 * g + h) * 66 + w];
    }
    if (tid < 2) sB[tid] = CB[2 * g + tid];

    // Q extended tile (rows q0-2 .. q0+QB+2), zero-filled OOB
    const float4* Q4 = (const float4*)Q;
    for (int idx = tid; idx < 2 * QE * 16; idx += 256) {
        int h = idx / (QE * 16);
        int rem = idx - h * QE * 16;
        int qe = rem >> 4, d4 = rem & 15;
        int r = q0 - 2 + qe;
        float4 val = make_float4(0.f, 0.f, 0.f, 0.f);
        if (r >= 0 && r < SS)
            val = Q4[((2 * g + h) * SS + r) * 16 + d4];
        *(float4*)&sQ[(h * QE + qe) * DP + (d4 << 2)] = val;
    }

    // online-softmax state: owned by conv-mapping threads (h=ch, row=cq)
    const int ch = tid >> 7;        // head-in-group 0/1
    const int cq = (tid >> 2) & 31; // query row in tile
    const int ck = tid & 3;         // 4 lanes per row, 8 keys each
    float m_run = -INFINITY, l_run = 0.f;

    // accumulators: [rr][i][j], rr covers (q,d4) position pairs
    float4 acc[2][2][2];
#pragma unroll
    for (int rr = 0; rr < 2; ++rr)
#pragma unroll
        for (int i = 0; i < 2; ++i)
#pragma unroll
            for (int j = 0; j < 2; ++j)
                acc[rr][i][j] = make_float4(0.f, 0.f, 0.f, 0.f);

    const float4* K4 = (const float4*)K;
    const float4* V4 = (const float4*)V;

    for (int kt = 0; kt <= tile; ++kt) {
        const int k0 = kt * KB;
        __syncthreads(); // previous tile's consumers done with sKV/sS/sP

        // K extended tile (cols k0-5 .. k0+KB+4), zero-filled OOB
        for (int idx = tid; idx < 2 * KE * 16; idx += 256) {
            int h = idx / (KE * 16);
            int rem = idx - h * KE * 16;
            int ke = rem >> 4, d4 = rem & 15;
            int c = k0 - 5 + ke;
            float4 val = make_float4(0.f, 0.f, 0.f, 0.f);
            if (c >= 0 && c < SS)
                val = K4[((2 * g + h) * SS + c) * 16 + d4];
            *(float4*)&sKV[(h * KE + ke) * DP + (d4 << 2)] = val;
        }
        __syncthreads();

        // masked scores on the extended tile: 2*37*42 dot-products of length 64
        for (int item = tid; item < 2 * QE * KE; item += 256) {
            int h = item / (QE * KE);
            int rem = item - h * QE * KE;
            int qe = rem / KE, ke = rem - qe * KE;
            const float4* qr = (const float4*)&sQ[(h * QE + qe) * DP];
            const float4* kr = (const float4*)&sKV[(h * KE + ke) * DP];
            float a = 0.f;
#pragma unroll
            for (int d4 = 0; d4 < 16; ++d4) {
                float4 x = qr[d4], y = kr[d4];
                a = fmaf(x.x, y.x, a);
                a = fmaf(x.y, y.y, a);
                a = fmaf(x.z, y.z, a);
                a = fmaf(x.w, y.w, a);
            }
            int r = q0 - 2 + qe, c = k0 - 5 + ke;
            sS[(h * QE + qe) * SPITCH + ke] = (c <= r) ? a * 0.125f : 0.f;
        }
        __syncthreads();

        // V tile load (reuses sKV rows 0..31 per head; K no longer needed)
        for (int idx = tid; idx < 2 * KB * 16; idx += 256) {
            int h = idx / (KB * 16);
            int rem = idx - h * KB * 16;
            int kk = rem >> 4, d4 = rem & 15;
            float4 val = V4[((2 * g + h) * SS + (k0 + kk)) * 16 + d4];
            *(float4*)&sKV[(h * KE + kk) * DP + (d4 << 2)] = val;
        }

        // depthwise 6x11 conv + bias + causal re-mask + online softmax
        {
            float vals[8];
            const int r = q0 + cq;
            float tmax = -INFINITY;
#pragma unroll
            for (int kk = 0; kk < 8; ++kk) {
                int kc = ck * 8 + kk;
                float a = sB[ch];
#pragma unroll
                for (int i = 0; i < 6; ++i) {
                    const float* srow = &sS[(ch * QE + cq + i) * SPITCH + kc];
#pragma unroll
                    for (int j = 0; j < 11; ++j)
                        a = fmaf(sW[ch][i * 11 + j], srow[j], a);
                }
                if (k0 + kc > r) a = -1e9f;
                vals[kk] = a;
                tmax = fmaxf(tmax, a);
            }
            tmax = fmaxf(tmax, __shfl_xor(tmax, 1));
            tmax = fmaxf(tmax, __shfl_xor(tmax, 2));
            float mnew = fmaxf(m_run, tmax);
            float resc = __expf(m_run - mnew); // m_run=-inf first tile -> 0
            float psum = 0.f;
#pragma unroll
            for (int kk = 0; kk < 8; ++kk) {
                float p = __expf(vals[kk] - mnew);
                sP[(ch * QB + cq) * PPITCH + ck * 8 + kk] = p;
                psum += p;
            }
            psum += __shfl_xor(psum, 1);
            psum += __shfl_xor(psum, 2);
            l_run = l_run * resc + psum;
            m_run = mnew;
            if (ck == 0) sResc[ch][cq] = resc;
        }
        __syncthreads();

        // accumulator update: acc[i][j] = acc[i][j]*resc_i + P_i @ V_j
#pragma unroll
        for (int rr = 0; rr < 2; ++rr) {
            int p = tid + (rr << 8);
            int qq = p >> 4, d4 = p & 15;
            float r0 = sResc[0][qq], r1 = sResc[1][qq];
            SCALE4(acc[rr][0][0], r0);
            SCALE4(acc[rr][0][1], r0);
            SCALE4(acc[rr][1][0], r1);
            SCALE4(acc[rr][1][1], r1);
            const float* P0 = &sP[qq * PPITCH];
            const float* P1 = &sP[(QB + qq) * PPITCH];
            const float* V0b = &sKV[0 * KE * DP + (d4 << 2)];
            const float* V1b = &sKV[1 * KE * DP + (d4 << 2)];
            for (int kk = 0; kk < KB; ++kk) {
                float p0 = P0[kk], p1 = P1[kk];
                float4 v0 = *(const float4*)&V0b[kk * DP];
                float4 v1 = *(const float4*)&V1b[kk * DP];
                FMA4(acc[rr][0][0], p0, v0);
                FMA4(acc[rr][0][1], p0, v1);
                FMA4(acc[rr][1][0], p1, v0);
                FMA4(acc[rr][1][1], p1, v1);
            }
        }
    }

    __syncthreads();
    if (ck == 0) sL[ch][cq] = l_run;
    __syncthreads();

    // head mixing + 1/l + LayerNorm over D, write out
    const float m00 = MIX[g * 4 + 0], m01 = MIX[g * 4 + 1];
    const float m10 = MIX[g * 4 + 2], m11 = MIX[g * 4 + 3];
    const float4* G4 = (const float4*)GAM;
    const float4* B4 = (const float4*)BET;
#pragma unroll
    for (int rr = 0; rr < 2; ++rr) {
        int p = tid + (rr << 8);
        int qq = p >> 4, d4 = p & 15;
        float il0 = 1.f / sL[0][qq];
        float il1 = 1.f / sL[1][qq];
        float4 gm = G4[d4], bt = B4[d4];
#pragma unroll
        for (int j = 0; j < 2; ++j) {
            float c0 = ((j == 0) ? m00 : m01) * il0;
            float c1 = ((j == 0) ? m10 : m11) * il1;
            float4 A0 = acc[rr][0][j], A1 = acc[rr][1][j];
            float4 o;
            o.x = c0 * A0.x + c1 * A1.x;
            o.y = c0 * A0.y + c1 * A1.y;
            o.z = c0 * A0.z + c1 * A1.z;
            o.w = c0 * A0.w + c1 * A1.w;
            float s1 = o.x + o.y + o.z + o.w;
            float s2 = o.x * o.x + o.y * o.y + o.z * o.z + o.w * o.w;
#pragma unroll
            for (int off = 1; off < 16; off <<= 1) {
                s1 += __shfl_xor(s1, off);
                s2 += __shfl_xor(s2, off);
            }
            float mean = s1 * (1.f / 64.f);
            float var = s2 * (1.f / 64.f) - mean * mean;
            float rs = rsqrtf(var + 1e-5f);
            float4 ov;
            ov.x = (o.x - mean) * rs * gm.x + bt.x;
            ov.y = (o.y - mean) * rs * gm.y + bt.y;
            ov.z = (o.z - mean) * rs * gm.z + bt.z;
            ov.w = (o.w - mean) * rs * gm.w + bt.w;
            *(float4*)&OUT[(((2 * g + j) * SS + (q0 + qq)) << 6) + (d4 << 2)] = ov;
        }
    }
}

extern "C" void kernel_launch(void* const* d_in, const int* in_sizes, int n_in,
                              void* d_out, int out_size, void* d_ws, size_t ws_size,
                              hipStream_t stream) {
    const float* q = (const float*)d_in[0];
    const float* k = (const float*)d_in[1];
    const float* v = (const float*)d_in[2];
    const float* cw = (const float*)d_in[3];
    const float* cb = (const float*)d_in[4];
    const float* mix = (const float*)d_in[5];
    const float* gam = (const float*)d_in[6];
    const float* bet = (const float*)d_in[7];
    float* out = (float*)d_out;

    dim3 grid(GG * NT);
    dim3 block(256);
    hipLaunchKernelGGL(mta_fused, grid, block, 0, stream,
                       q, k, v, cw, cb, mix, gam, bet, out);
}

// Round 2
// 381.524 us; speedup vs baseline: 2.5065x; 2.5065x over previous
//
#include <hip/hip_runtime.h>
#include <math.h>

#define SS 2048
#define QB 32
#define NT 64
#define QP 72   // bf16 pitch, sQ/sK rows (144 B, 16B-mult, 2-way banks)
#define VP 40   // bf16 pitch, sVt rows (80 B)
#define SP 52   // f32 pitch, sS rows (208 B)
#define PP 40   // bf16 pitch, sP rows

typedef __attribute__((ext_vector_type(8))) short s8v;
typedef __attribute__((ext_vector_type(4))) float f4v;

__device__ __forceinline__ unsigned short f2b(float x) {
    union { float f; unsigned u; } v; v.f = x;
    unsigned r = v.u + 0x7FFFu + ((v.u >> 16) & 1u);
    return (unsigned short)(r >> 16);
}

__device__ __forceinline__ unsigned long long pack4(float4 v) {
    return (unsigned long long)f2b(v.x) | ((unsigned long long)f2b(v.y) << 16)
         | ((unsigned long long)f2b(v.z) << 32) | ((unsigned long long)f2b(v.w) << 48);
}

__global__ __launch_bounds__(256, 2)
void mta_mfma(const float* __restrict__ Q, const float* __restrict__ K,
              const float* __restrict__ V, const float* __restrict__ CW,
              const float* __restrict__ CB, const float* __restrict__ MIX,
              const float* __restrict__ GAM, const float* __restrict__ BET,
              float* __restrict__ OUT)
{
    __shared__ __align__(16) unsigned short sQ[2 * 48 * QP];  // 13824 B
    __shared__ __align__(16) unsigned short sK[2 * 48 * QP];  // 13824 B
    __shared__ __align__(16) unsigned short sVt[2 * 64 * VP]; // 10240 B (V transposed)
    __shared__ __align__(16) float sS[2 * 48 * SP];           // 19968 B (f32 masked scores; reused as sOut)
    __shared__ __align__(16) unsigned short sP[2 * 32 * PP];  // 5120 B
    __shared__ float sResc[2][32];
    __shared__ float sL[2][32];
    __shared__ float sW[2][66];
    __shared__ float sB[2];

    const int tid = threadIdx.x;
    const int g = blockIdx.x & 7;
    const int u = blockIdx.x >> 3;

    const int wv = tid >> 6, lane = tid & 63;
    const int lrow = lane & 15;            // A/B fragment row, C col
    const int lk8 = (lane >> 4) << 3;      // fragment k-offset (0,8,16,24)
    const int crow4 = (lane >> 4) << 2;    // C row base

    const int ch = tid >> 7, cq = (tid >> 2) & 31, ck = tid & 3; // conv/softmax mapping
    const int i_pv = wv >> 1, j_pv = wv & 1;                      // PV wave = (i,j)

    for (int idx = tid; idx < 132; idx += 256) {
        int h = idx / 66, w = idx - h * 66;
        sW[h][w] = CW[(2 * g + h) * 66 + w];
    }
    if (tid < 2) sB[tid] = CB[2 * g + tid];
    const float mixc = MIX[g * 4 + i_pv * 2 + j_pv];

    const float4* Q4 = (const float4*)Q;
    const float4* K4 = (const float4*)K;
    const float4* V4 = (const float4*)V;

    for (int ti = 0; ti < 2; ++ti) {
        const int tile = ti ? u : (NT - 1 - u);   // heavy tile first; pair sums to 65 iters
        const int q0 = tile * QB;

        __syncthreads();
        // ---- stage extended Q tile (rows q0-2 .. q0+45), bf16 ----
        for (int idx = tid; idx < 1536; idx += 256) {
            int h = idx / 768, rem = idx - h * 768;
            int e = rem >> 4, d4 = rem & 15;
            int r = q0 - 2 + e;
            float4 val = make_float4(0.f, 0.f, 0.f, 0.f);
            if (r >= 0 && r < SS) val = Q4[((2 * g + h) * SS + r) * 16 + d4];
            *(unsigned long long*)&sQ[(h * 48 + e) * QP + (d4 << 2)] = pack4(val);
        }

        float m_run = -INFINITY, l_run = 0.f;
        f4v acc[2][4];
#pragma unroll
        for (int mt = 0; mt < 2; ++mt)
#pragma unroll
            for (int nt = 0; nt < 4; ++nt) acc[mt][nt] = f4v{0.f, 0.f, 0.f, 0.f};

        for (int kt = 0; kt <= tile; ++kt) {
            const int k0 = kt * QB;
            __syncthreads(); // prev PV done with sVt/sP; prev scores done with sK

            // ---- stage extended K tile (cols k0-5 .. k0+42), bf16 ----
            for (int idx = tid; idx < 1536; idx += 256) {
                int h = idx / 768, rem = idx - h * 768;
                int f = rem >> 4, d4 = rem & 15;
                int c = k0 - 5 + f;
                float4 val = make_float4(0.f, 0.f, 0.f, 0.f);
                if (c >= 0 && c < SS) val = K4[((2 * g + h) * SS + c) * 16 + d4];
                *(unsigned long long*)&sK[(h * 48 + f) * QP + (d4 << 2)] = pack4(val);
            }
            // ---- stage V transposed: sVt[h][d][k] (lane order bank-friendly) ----
            for (int idx = tid; idx < 1024; idx += 256) {
                int h = idx >> 9, d4 = (idx >> 5) & 15, kk = idx & 31;
                float4 val = V4[((2 * g + h) * SS + k0 + kk) * 16 + d4];
                int d = d4 << 2;
                sVt[(h * 64 + d + 0) * VP + kk] = f2b(val.x);
                sVt[(h * 64 + d + 1) * VP + kk] = f2b(val.y);
                sVt[(h * 64 + d + 2) * VP + kk] = f2b(val.z);
                sVt[(h * 64 + d + 3) * VP + kk] = f2b(val.w);
            }
            __syncthreads();

            // ---- scores: 2 heads x 3x3 16-tiles, K=64 (2 MFMA k-steps) ----
            for (int job = wv; job < 18; job += 4) {
                int h = job / 9, r9 = job - h * 9;
                int mt = r9 / 3, nt = r9 - mt * 3;
                const unsigned short* qrow = &sQ[(h * 48 + mt * 16 + lrow) * QP + lk8];
                const unsigned short* krow = &sK[(h * 48 + nt * 16 + lrow) * QP + lk8];
                f4v c = f4v{0.f, 0.f, 0.f, 0.f};
                c = __builtin_amdgcn_mfma_f32_16x16x32_bf16(*(const s8v*)qrow,
                                                            *(const s8v*)krow, c, 0, 0, 0);
                c = __builtin_amdgcn_mfma_f32_16x16x32_bf16(*(const s8v*)(qrow + 32),
                                                            *(const s8v*)(krow + 32), c, 0, 0, 0);
                int col = nt * 16 + lrow;
                int c_abs = k0 - 5 + col;
                int rbase = mt * 16 + crow4;
#pragma unroll
                for (int r = 0; r < 4; ++r) {
                    int r_abs = q0 - 2 + rbase + r;
                    sS[(h * 48 + rbase + r) * SP + col] = (c_abs <= r_abs) ? c[r] * 0.125f : 0.f;
                }
            }
            __syncthreads();

            // ---- conv (sliding window) + causal re-mask + online softmax ----
            {
                float a8[8];
#pragma unroll
                for (int kk = 0; kk < 8; ++kk) a8[kk] = sB[ch];
#pragma unroll
                for (int i = 0; i < 6; ++i) {
                    const float* srow = &sS[(ch * 48 + cq + i) * SP + (ck << 3)];
                    float4 x0 = *(const float4*)&srow[0];
                    float4 x1 = *(const float4*)&srow[4];
                    float4 x2 = *(const float4*)&srow[8];
                    float4 x3 = *(const float4*)&srow[12];
                    float4 x4 = *(const float4*)&srow[16];
                    float s[20] = {x0.x, x0.y, x0.z, x0.w, x1.x, x1.y, x1.z, x1.w,
                                   x2.x, x2.y, x2.z, x2.w, x3.x, x3.y, x3.z, x3.w,
                                   x4.x, x4.y, x4.z, x4.w};
                    float wr[11];
#pragma unroll
                    for (int jj = 0; jj < 11; ++jj) wr[jj] = sW[ch][i * 11 + jj];
#pragma unroll
                    for (int kk = 0; kk < 8; ++kk)
#pragma unroll
                        for (int jj = 0; jj < 11; ++jj)
                            a8[kk] = fmaf(wr[jj], s[kk + jj], a8[kk]);
                }
                const int r_abs = q0 + cq;
                float tmax = -INFINITY;
#pragma unroll
                for (int kk = 0; kk < 8; ++kk) {
                    int c_abs = k0 + (ck << 3) + kk;
                    if (c_abs > r_abs) a8[kk] = -1e9f;
                    tmax = fmaxf(tmax, a8[kk]);
                }
                tmax = fmaxf(tmax, __shfl_xor(tmax, 1));
                tmax = fmaxf(tmax, __shfl_xor(tmax, 2));
                float mnew = fmaxf(m_run, tmax);
                float resc = __expf(m_run - mnew); // first tile: exp(-inf)=0
                float psum = 0.f;
#pragma unroll
                for (int kk = 0; kk < 8; ++kk) {
                    float p = __expf(a8[kk] - mnew);
                    psum += p;
                    sP[(ch * 32 + cq) * PP + (ck << 3) + kk] = f2b(p);
                }
                psum += __shfl_xor(psum, 1);
                psum += __shfl_xor(psum, 2);
                l_run = l_run * resc + psum;
                m_run = mnew;
                if (ck == 0) sResc[ch][cq] = resc;
            }
            __syncthreads();

            // ---- PV: wave (i,j) accumulates P_i @ V_j into MFMA fragments ----
            {
#pragma unroll
                for (int mt = 0; mt < 2; ++mt)
#pragma unroll
                    for (int r = 0; r < 4; ++r) {
                        float f = sResc[i_pv][mt * 16 + crow4 + r];
#pragma unroll
                        for (int nt = 0; nt < 4; ++nt) acc[mt][nt][r] *= f;
                    }
                s8v vb[4];
#pragma unroll
                for (int nt = 0; nt < 4; ++nt)
                    vb[nt] = *(const s8v*)&sVt[(j_pv * 64 + nt * 16 + lrow) * VP + lk8];
#pragma unroll
                for (int mt = 0; mt < 2; ++mt) {
                    s8v a = *(const s8v*)&sP[(i_pv * 32 + mt * 16 + lrow) * PP + lk8];
#pragma unroll
                    for (int nt = 0; nt < 4; ++nt)
                        acc[mt][nt] = __builtin_amdgcn_mfma_f32_16x16x32_bf16(a, vb[nt], acc[mt][nt], 0, 0, 0);
                }
            }
        } // kt

        if (ck == 0) sL[ch][cq] = l_run;
        __syncthreads();

        // ---- head mixing into sOut (reuse sS, pitch 68 f32) ----
        float* sO = sS;
        if (i_pv == 0) {
#pragma unroll
            for (int mt = 0; mt < 2; ++mt)
#pragma unroll
                for (int r = 0; r < 4; ++r) {
                    int row = mt * 16 + crow4 + r;
                    float cc = mixc / sL[0][row];
#pragma unroll
                    for (int nt = 0; nt < 4; ++nt)
                        sO[(j_pv * 32 + row) * 68 + nt * 16 + lrow] = acc[mt][nt][r] * cc;
                }
        }
        __syncthreads();
        if (i_pv == 1) {
#pragma unroll
            for (int mt = 0; mt < 2; ++mt)
#pragma unroll
                for (int r = 0; r < 4; ++r) {
                    int row = mt * 16 + crow4 + r;
                    float cc = mixc / sL[1][row];
#pragma unroll
                    for (int nt = 0; nt < 4; ++nt)
                        sO[(j_pv * 32 + row) * 68 + nt * 16 + lrow] += acc[mt][nt][r] * cc;
                }
        }
        __syncthreads();

        // ---- LayerNorm over D + store ----
        const float4* G4 = (const float4*)GAM;
        const float4* B4 = (const float4*)BET;
#pragma unroll
        for (int it = 0; it < 4; ++it) {
            int p = tid + (it << 8);
            int d4 = p & 15, rowj = p >> 4; // 0..63: j = rowj>>5, qq = rowj&31
            int j = rowj >> 5, qq = rowj & 31;
            float4 o = *(const float4*)&sO[rowj * 68 + (d4 << 2)];
            float s1 = o.x + o.y + o.z + o.w;
            float s2 = o.x * o.x + o.y * o.y + o.z * o.z + o.w * o.w;
#pragma unroll
            for (int off = 1; off < 16; off <<= 1) {
                s1 += __shfl_xor(s1, off);
                s2 += __shfl_xor(s2, off);
            }
            float mean = s1 * (1.f / 64.f);
            float var = s2 * (1.f / 64.f) - mean * mean;
            float rs = rsqrtf(var + 1e-5f);
            float4 gm = G4[d4], bt = B4[d4];
            float4 ov;
            ov.x = (o.x - mean) * rs * gm.x + bt.x;
            ov.y = (o.y - mean) * rs * gm.y + bt.y;
            ov.z = (o.z - mean) * rs * gm.z + bt.z;
            ov.w = (o.w - mean) * rs * gm.w + bt.w;
            *(float4*)&OUT[(((2 * g + j) * SS + q0 + qq) << 6) + (d4 << 2)] = ov;
        }
    } // ti
}

extern "C" void kernel_launch(void* const* d_in, const int* in_sizes, int n_in,
                              void* d_out, int out_size, void* d_ws, size_t ws_size,
                              hipStream_t stream) {
    const float* q = (const float*)d_in[0];
    const float* k = (const float*)d_in[1];
    const float* v = (const float*)d_in[2];
    const float* cw = (const float*)d_in[3];
    const float* cb = (const float*)d_in[4];
    const float* mix = (const float*)d_in[5];
    const float* gam = (const float*)d_in[6];
    const float* bet = (const float*)d_in[7];
    float* out = (float*)d_out;

    dim3 grid(8 * 32); // 8 groups x 32 balanced tile-pairs
    dim3 block(256);
    hipLaunchKernelGGL(mta_mfma, grid, block, 0, stream,
                       q, k, v, cw, cb, mix, gam, bet, out);
}